// Round 5
// baseline (846.225 us; speedup 1.0000x reference)
//
#include <hip/hip_runtime.h>
#include <hip/hip_bf16.h>
#include <math.h>

#define DI 384
#define NSEQ 256
#define BB 64
#define DOUT 512
#define SID 73920
#define EPSV 1e-5f

typedef float f32x4 __attribute__((ext_vector_type(4)));
typedef short s16x8 __attribute__((ext_vector_type(8)));

// ---------------- small kernels ----------------

__global__ __launch_bounds__(256) void k_weights(const float* __restrict__ graph,
                                                 float* __restrict__ W) {
  int row = blockIdx.x;
  const float* g = graph + (size_t)row * NSEQ;
  float* w = W + (size_t)row * NSEQ;
  int t = threadIdx.x;
  float v = g[t];
  __shared__ float red[256];
  red[t] = v;
  __syncthreads();
  for (int s = 128; s > 0; s >>= 1) {
    if (t < s) red[t] += red[t + s];
    __syncthreads();
  }
  float deg = red[0] + EPSV;
  w[t] = v / deg;
}

__global__ __launch_bounds__(256) void k_colw(const float* __restrict__ W,
                                              float* __restrict__ colw) {
  int b = blockIdx.x;
  int j = threadIdx.x;
  const float* w = W + (size_t)b * NSEQ * NSEQ + j;
  float s = 0.f;
  for (int n = 0; n < NSEQ; n++) s += w[(size_t)n * NSEQ];
  colw[b * NSEQ + j] = s;
}

__global__ __launch_bounds__(384) void k_wmean(const float* __restrict__ colw,
                                               const float* __restrict__ tokens,
                                               float* __restrict__ wm) {
  int b = blockIdx.x;
  int d = threadIdx.x;
  const float* t = tokens + (size_t)b * NSEQ * DI + d;
  const float* cw = colw + b * NSEQ;
  float s = 0.f;
  for (int n = 0; n < NSEQ; n++) s += cw[n] * t[(size_t)n * DI];
  wm[b * DI + d] = s;
}

// ZT[b][d][n] = tokens[b][n][d] - wm[b][d]
__global__ __launch_bounds__(256) void k_zcT(const float* __restrict__ tokens,
                                             const float* __restrict__ wm,
                                             float* __restrict__ ZT) {
  int b = blockIdx.z;
  int d0 = blockIdx.x * 64, n0 = blockIdx.y * 64;
  __shared__ float ld[64][68];
  const float* Tb = tokens + (size_t)b * NSEQ * DI;
  const float* wmb = wm + (size_t)b * DI;
  float* Zb = ZT + (size_t)b * DI * NSEQ;
#pragma unroll
  for (int i = 0; i < 4; i++) {
    int sl = threadIdx.x + i * 256;
    int r = sl >> 4, q = sl & 15;
    float4 v = *(const float4*)&Tb[(size_t)(n0 + r) * DI + d0 + q * 4];
    float4 m = *(const float4*)&wmb[d0 + q * 4];
    v.x -= m.x; v.y -= m.y; v.z -= m.z; v.w -= m.w;
    *(float4*)&ld[r][q * 4] = v;
  }
  __syncthreads();
#pragma unroll
  for (int i = 0; i < 4; i++) {
    int sl = threadIdx.x + i * 256;
    int dl = sl >> 4, q = sl & 15;
    float4 v;
    v.x = ld[q * 4 + 0][dl];
    v.y = ld[q * 4 + 1][dl];
    v.z = ld[q * 4 + 2][dl];
    v.w = ld[q * 4 + 3][dl];
    *(float4*)&Zb[(size_t)(d0 + dl) * NSEQ + n0 + q * 4] = v;
  }
}

__global__ __launch_bounds__(256) void k_trace(const float* __restrict__ M2,
                                               float* __restrict__ tr) {
  int b = blockIdx.x;
  int t = threadIdx.x;
  float s = 0.f;
  for (int d = t; d < DI; d += 256)
    s += M2[(size_t)b * DI * DI + (size_t)d * DI + d];
  __shared__ float red[256];
  red[t] = s;
  __syncthreads();
  for (int st = 128; st > 0; st >>= 1) {
    if (t < st) red[t] += red[t + st];
    __syncthreads();
  }
  if (t == 0) tr[b] = red[0];
}

// MnN = M2/(tr+eps), MnT = transpose(MnN)
__global__ __launch_bounds__(256) void k_scaleT(const float* __restrict__ M2,
                                                const float* __restrict__ tr,
                                                float* __restrict__ MnN,
                                                float* __restrict__ MnT) {
  int b = blockIdx.z;
  int c0 = blockIdx.x * 64, r0 = blockIdx.y * 64;
  __shared__ float ld[64][68];
  float inv = 1.0f / (tr[b] + EPSV);
  const float* Xb = M2 + (size_t)b * 147456;
  float* Nb = MnN + (size_t)b * 147456;
  float* Tb = MnT + (size_t)b * 147456;
#pragma unroll
  for (int i = 0; i < 4; i++) {
    int sl = threadIdx.x + i * 256;
    int r = sl >> 4, q = sl & 15;
    float4 v = *(const float4*)&Xb[(size_t)(r0 + r) * 384 + c0 + q * 4];
    v.x *= inv; v.y *= inv; v.z *= inv; v.w *= inv;
    *(float4*)&ld[r][q * 4] = v;
    *(float4*)&Nb[(size_t)(r0 + r) * 384 + c0 + q * 4] = v;
  }
  __syncthreads();
#pragma unroll
  for (int i = 0; i < 4; i++) {
    int sl = threadIdx.x + i * 256;
    int n = sl >> 4, q = sl & 15;
    float4 v;
    v.x = ld[q * 4 + 0][n];
    v.y = ld[q * 4 + 1][n];
    v.z = ld[q * 4 + 2][n];
    v.w = ld[q * 4 + 3][n];
    *(float4*)&Tb[(size_t)(c0 + n) * 384 + r0 + q * 4] = v;
  }
}

// fp32 batched 384x384 transpose via LDS
__global__ __launch_bounds__(256) void k_transpose(const float* __restrict__ X,
                                                   float* __restrict__ XT) {
  int b = blockIdx.z;
  int c0 = blockIdx.x * 64, r0 = blockIdx.y * 64;
  __shared__ float ld[64][68];
  const float* Xb = X + (size_t)b * 147456;
  float* Tb = XT + (size_t)b * 147456;
#pragma unroll
  for (int i = 0; i < 4; i++) {
    int sl = threadIdx.x + i * 256;
    int r = sl >> 4, q = sl & 15;
    *(float4*)&ld[r][q * 4] = *(const float4*)&Xb[(size_t)(r0 + r) * 384 + c0 + q * 4];
  }
  __syncthreads();
#pragma unroll
  for (int i = 0; i < 4; i++) {
    int sl = threadIdx.x + i * 256;
    int n = sl >> 4, q = sl & 15;
    float4 v;
    v.x = ld[q * 4 + 0][n];
    v.y = ld[q * 4 + 1][n];
    v.z = ld[q * 4 + 2][n];
    v.w = ld[q * 4 + 3][n];
    *(float4*)&Tb[(size_t)(c0 + n) * 384 + r0 + q * 4] = v;
  }
}

// ---------------- split-bf16 MFMA NT-GEMM (swizzled LDS, 2-phase) ----------
// C[m][n] = sum_k A[m][k] * BT[n][k]; fp32 split hi/mid/lo bf16 (RNE), 6 passes.

// LDS plane = 128 rows x 4 slots of 16B; swizzled slot: (4*row+s) ^ (row&7).
// Bijective; both write phase (2 lanes/row x 2 slots) and read phase
// (16 rows x 4 slots) spread evenly over all 8 bank groups.
__device__ __forceinline__ int swzoff(int row, int s) {
  return (((row << 2) + s) ^ (row & 7)) << 3;  // in shorts
}

__device__ __forceinline__ void split_store(const f32x4* v4, short* base, int row,
                                            int s0) {
  const float* vf = (const float*)v4;
  union U { unsigned u[4]; s16x8 v8; };
  U uh[2], um[2], ul[2];
#pragma unroll
  for (int g = 0; g < 2; g++) {
#pragma unroll
    for (int p = 0; p < 4; p++) {
      float a = vf[g * 8 + 2 * p], c = vf[g * 8 + 2 * p + 1];
      __hip_bfloat162 hb = __float22bfloat162_rn(make_float2(a, c));
      unsigned hu; __builtin_memcpy(&hu, &hb, 4);
      float ra = a - __uint_as_float(hu << 16);
      float rc = c - __uint_as_float(hu & 0xFFFF0000u);
      __hip_bfloat162 mb = __float22bfloat162_rn(make_float2(ra, rc));
      unsigned mu; __builtin_memcpy(&mu, &mb, 4);
      float qa = ra - __uint_as_float(mu << 16);
      float qc = rc - __uint_as_float(mu & 0xFFFF0000u);
      __hip_bfloat162 lb = __float22bfloat162_rn(make_float2(qa, qc));
      unsigned lu; __builtin_memcpy(&lu, &lb, 4);
      uh[g].u[p] = hu; um[g].u[p] = mu; ul[g].u[p] = lu;
    }
  }
  int o0 = swzoff(row, s0), o1 = swzoff(row, s0 + 1);
  *(s16x8*)(base + o0) = uh[0].v8;
  *(s16x8*)(base + o1) = uh[1].v8;
  *(s16x8*)(base + 4096 + o0) = um[0].v8;
  *(s16x8*)(base + 4096 + o1) = um[1].v8;
  *(s16x8*)(base + 8192 + o0) = ul[0].v8;
  *(s16x8*)(base + 8192 + o1) = ul[1].v8;
}

__device__ __forceinline__ s16x8 frag(const short* base, int plane, int row, int lg) {
  return *(const s16x8*)(base + plane * 4096 + swzoff(row, lg));
}

// MODE 0: C = alpha*acc + diagAdd*I (ldc=384)
// MODE 1: Y2T epilogue (reads pMn, pP1T; writes transposed)
// MODE 2: V = triu(alpha*acc)/sqrt(tr+eps), packed per batch (b*SID)
template <int MODE>
__global__ __launch_bounds__(256, 3) void gemm_nt(
    const float* __restrict__ pA, const float* __restrict__ pBT,
    float* __restrict__ pC, const float* __restrict__ pMn,
    const float* __restrict__ pP1T, const float* __restrict__ trv, int K, int lda,
    int ldb, long sA, long sB, long sC, float alpha, float diagAdd) {
  __shared__ short As[3 * 128 * 32];
  __shared__ short Bs[3 * 128 * 32];
  int b = blockIdx.z;
  int m0 = blockIdx.y * 128, n0 = blockIdx.x * 128;
  const float* Ab = pA + (size_t)b * sA;
  const float* Bb = pBT + (size_t)b * sB;
  int tid = threadIdx.x;
  int lane = tid & 63, wid = tid >> 6;
  int wm = wid >> 1, wn = wid & 1;
  int lr = lane & 15, lg = lane >> 4;
  int sr = tid >> 1, s0 = (tid & 1) * 2;
  int koff = (tid & 1) * 16;
  const float* Aptr = Ab + (size_t)(m0 + sr) * lda + koff;
  const float* Bptr = Bb + (size_t)(n0 + sr) * ldb + koff;
  f32x4 acc[4][4] = {};
  f32x4 ra[4], rb[4];

#pragma unroll
  for (int i = 0; i < 4; i++) {
    ra[i] = *(const f32x4*)(Aptr + i * 4);
    rb[i] = *(const f32x4*)(Bptr + i * 4);
  }
  split_store(ra, As, sr, s0);
  split_store(rb, Bs, sr, s0);
  __syncthreads();

  for (int k0 = 0; k0 < K; k0 += 32) {
    bool more = (k0 + 32) < K;
    if (more) {
#pragma unroll
      for (int i = 0; i < 4; i++) {
        ra[i] = *(const f32x4*)(Aptr + k0 + 32 + i * 4);
        rb[i] = *(const f32x4*)(Bptr + k0 + 32 + i * 4);
      }
    }
#pragma unroll
    for (int ib = 0; ib < 3; ib++) {
      s16x8 bfr[4];
#pragma unroll
      for (int ni = 0; ni < 4; ni++)
        bfr[ni] = frag(Bs, ib, wn * 64 + ni * 16 + lr, lg);
#pragma unroll
      for (int ia = 0; ia < 3; ia++) {
        if (ia + ib > 2) continue;
        s16x8 afr[4];
#pragma unroll
        for (int mi = 0; mi < 4; mi++)
          afr[mi] = frag(As, ia, wm * 64 + mi * 16 + lr, lg);
#pragma unroll
        for (int ni = 0; ni < 4; ni++)
#pragma unroll
          for (int mi = 0; mi < 4; mi++)
            acc[mi][ni] = __builtin_amdgcn_mfma_f32_16x16x32_bf16(
                afr[mi], bfr[ni], acc[mi][ni], 0, 0, 0);
      }
    }
    __syncthreads();
    if (more) {
      split_store(ra, As, sr, s0);
      split_store(rb, Bs, sr, s0);
    }
    __syncthreads();
  }

  const size_t cb = (size_t)b * sC;
  float invs = 0.f;
  if (MODE == 2) invs = 1.0f / sqrtf(trv[b] + EPSV);
#pragma unroll
  for (int mi = 0; mi < 4; mi++)
#pragma unroll
    for (int ni = 0; ni < 4; ni++)
#pragma unroll
      for (int j = 0; j < 4; j++) {
        int row = m0 + wm * 64 + mi * 16 + lg * 4 + j;
        int col = n0 + wn * 64 + ni * 16 + lr;
        float v = acc[mi][ni][j];
        if (MODE == 0) {
          float o = alpha * v;
          if (row == col) o += diagAdd;
          pC[cb + (size_t)row * 384 + col] = o;
        } else if (MODE == 1) {
          float mn = pMn[cb + (size_t)row * 384 + col];
          float p1 = pP1T[cb + (size_t)col * 384 + row];
          float y2 = -1.875f * mn + 0.75f * p1 - 0.125f * v;
          if (row == col) y2 += 2.25f;
          pC[cb + (size_t)col * 384 + row] = y2;  // Y2T
        } else {
          if (col >= row) {
            long idx = (long)b * SID + (long)row * 384 - (long)row * (row - 1) / 2 +
                       (col - row);
            pC[idx] = alpha * v * invs;
          }
        }
      }
}

// ---------------- final FC: out = gelu(V @ W2 + b2) ----------------
#define FC_KSTEPS 5
#define FC_NCH 231

__global__ __launch_bounds__(256) void k_fc(const float* __restrict__ V,
                                            const float* __restrict__ W2,
                                            float* __restrict__ part) {
  int ct = blockIdx.x;
  int kc = blockIdx.y;
  __shared__ float vt[64][68];
  __shared__ float wt[64][64];
  int tid = threadIdx.x;
  int cq = tid & 15, rq = tid >> 4;
  float acc[4][4] = {};
  int ks0 = kc * 320;
  for (int s = 0; s < FC_KSTEPS; s++) {
    int ks = ks0 + s * 64;
#pragma unroll
    for (int i = 0; i < 4; i++) {
      int sl = tid + i * 256;
      int m = sl >> 4, k4 = sl & 15;
      float4 v = *(const float4*)&V[(size_t)m * SID + ks + k4 * 4];
      vt[k4 * 4 + 0][m] = v.x;
      vt[k4 * 4 + 1][m] = v.y;
      vt[k4 * 4 + 2][m] = v.z;
      vt[k4 * 4 + 3][m] = v.w;
      int kk = sl >> 4, q = sl & 15;
      *(float4*)&wt[kk][q * 4] = *(const float4*)&W2[(size_t)(ks + kk) * DOUT + ct * 64 + q * 4];
    }
    __syncthreads();
#pragma unroll 8
    for (int kk = 0; kk < 64; kk++) {
      float4 a = *(const float4*)&vt[kk][rq * 4];
      float4 w = *(const float4*)&wt[kk][cq * 4];
      acc[0][0] += a.x * w.x; acc[0][1] += a.x * w.y; acc[0][2] += a.x * w.z; acc[0][3] += a.x * w.w;
      acc[1][0] += a.y * w.x; acc[1][1] += a.y * w.y; acc[1][2] += a.y * w.z; acc[1][3] += a.y * w.w;
      acc[2][0] += a.z * w.x; acc[2][1] += a.z * w.y; acc[2][2] += a.z * w.z; acc[2][3] += a.z * w.w;
      acc[3][0] += a.w * w.x; acc[3][1] += a.w * w.y; acc[3][2] += a.w * w.z; acc[3][3] += a.w * w.w;
    }
    __syncthreads();
  }
  float* p = part + (size_t)kc * (BB * DOUT) + ct * 64;
#pragma unroll
  for (int i = 0; i < 4; i++)
#pragma unroll
    for (int j = 0; j < 4; j++)
      p[(size_t)(rq * 4 + i) * DOUT + cq * 4 + j] = acc[i][j];
}

__global__ __launch_bounds__(256) void k_reduce(const float* __restrict__ part,
                                                const float* __restrict__ b2,
                                                float* __restrict__ out) {
  int idx = blockIdx.x * 256 + threadIdx.x;
  int c = idx & (DOUT - 1);
  float s = 0.f;
  for (int kc = 0; kc < FC_NCH; kc++) s += part[(size_t)kc * BB * DOUT + idx];
  float x = s + b2[c];
  out[idx] = 0.5f * x * (1.0f + erff(x * 0.70710678118654752f));
}

// ---------------- launch ----------------

extern "C" void kernel_launch(void* const* d_in, const int* in_sizes, int n_in,
                              void* d_out, int out_size, void* d_ws, size_t ws_size,
                              hipStream_t stream) {
  (void)in_sizes; (void)n_in; (void)out_size; (void)ws_size;
  const float* tokens = (const float*)d_in[0];
  const float* graph = (const float*)d_in[1];
  const float* W2 = (const float*)d_in[2];
  const float* b2 = (const float*)d_in[3];

  float* ws = (float*)d_ws;
  const long NM = 9437184L;  // 64*384*384
  float* s0 = ws;             // W -> M2 -> P1T -> TT
  float* s1 = ws + NM;        // ZT -> MnN -> Y2N -> part
  float* s2 = ws + 2 * NM;    // WZT(ld384) -> MnT -> Y2T -> V(packed)
  float* colw = ws + 3 * NM;
  float* wmv = colw + BB * NSEQ;
  float* trv = wmv + BB * DI;

  k_weights<<<BB * NSEQ, 256, 0, stream>>>(graph, s0);                 // W
  k_colw<<<BB, 256, 0, stream>>>(s0, colw);
  k_wmean<<<BB, 384, 0, stream>>>(colw, tokens, wmv);
  k_zcT<<<dim3(6, 4, BB), 256, 0, stream>>>(tokens, wmv, s1);          // ZT

  // WZT[e][n] = sum_k ZT[e][k] W[n][k]; M=384,N=256,K=256; stored ld=384 in s2
  gemm_nt<0><<<dim3(2, 3, BB), 256, 0, stream>>>(
      s1, s0, s2, nullptr, nullptr, nullptr, 256, 256, 256,
      98304L, 65536L, 147456L, 1.f, 0.f);
  // M2[d][e] = sum_n ZT[d][n] WZT[e][n]; M=N=384,K=256; WZT read ldb=384
  gemm_nt<0><<<dim3(3, 3, BB), 256, 0, stream>>>(
      s1, s2, s0, nullptr, nullptr, nullptr, 256, 256, 384,
      98304L, 147456L, 147456L, 1.f, 0.f);

  k_trace<<<BB, 256, 0, stream>>>(s0, trv);
  k_scaleT<<<dim3(6, 6, BB), 256, 0, stream>>>(s0, trv, s1, s2);       // MnN, MnT

  dim3 g33(3, 3, BB);
  // P1T = NT(MnT, MnN) -> s0
  gemm_nt<0><<<g33, 256, 0, stream>>>(s2, s1, s0, nullptr, nullptr, nullptr,
                                      384, 384, 384, 147456L, 147456L, 147456L,
                                      1.f, 0.f);
  // H = NT(MnN, P1T); epilogue writes Y2T -> s2
  gemm_nt<1><<<g33, 256, 0, stream>>>(s1, s0, s2, s1, s0, nullptr,
                                      384, 384, 384, 147456L, 147456L, 147456L,
                                      0.f, 0.f);
  // TT = 3I - NT(Y2T, MnN) -> s0
  gemm_nt<0><<<g33, 256, 0, stream>>>(s2, s1, s0, nullptr, nullptr, nullptr,
                                      384, 384, 384, 147456L, 147456L, 147456L,
                                      -1.f, 3.f);
  // Y2N = transpose(Y2T) -> s1
  k_transpose<<<dim3(6, 6, BB), 256, 0, stream>>>(s2, s1);
  // V = triu(0.5 * NT(Y2N, TT)) / sqrt(tr+eps) -> s2 (packed)
  gemm_nt<2><<<g33, 256, 0, stream>>>(s1, s0, s2, nullptr, nullptr, trv,
                                      384, 384, 384, 147456L, 147456L, 0L,
                                      0.5f, 0.f);

  // out = gelu(V @ W2 + b2)
  k_fc<<<dim3(8, FC_NCH), 256, 0, stream>>>(s2, W2, s1);
  k_reduce<<<(BB * DOUT) / 256, 256, 0, stream>>>(s1, b2, (float*)d_out);
}